// Round 6
// baseline (1627.132 us; speedup 1.0000x reference)
//
#include <hip/hip_runtime.h>
#include <hip/hip_bf16.h>
#include <math.h>

// Problem constants
#define TT   128   // timesteps
#define BB   256   // batch
#define DIN  256
#define DH   1024
#define DOUT 256

// 8 row-groups (32 batch rows) x 8 blocks/group (128 h-cols each).
// Block = 512 threads = 8 waves; wave owns 16 cols, W1h A-frags in REGISTERS
// (128 VGPR, loop-invariant). Per step the block stages the group's 64KB
// h-slab into LDS once (cooperative agent-scope loads, ONE latency exposure),
// then all waves read B-fragments from LDS. Coherent IF traffic: 4MB/step
// (vs 16MB in the 32-block layout). Sync: 8 producer-block epoch flags per
// group, agent-scope atomics only (R3-proven primitives; no inline asm).
#define NGM 8
#define NGN 8
#define MR  32
#define NC  128

typedef float  floatx4 __attribute__((ext_vector_type(4)));
typedef short  shortx8 __attribute__((ext_vector_type(8)));
typedef unsigned long long u64;

// LDS slab strides in shorts; S_Q padded 256->264 so staging writes spread
// banks (reads: bank = ((lr+q)&7)*4, 2-way per 16-lane phase = free).
#define S_LR 8
#define S_RT 128
#define S_Q  264
#define S_KS 1056
#define HB_SHORTS (32 * S_KS)   // 33792 shorts = 67.6 KB

__device__ __forceinline__ short f2bf(float f) {
    union { float f; unsigned u; } v; v.f = f;
    unsigned r = v.u + 0x7fffu + ((v.u >> 16) & 1u);   // RNE, inputs never NaN
    return (short)(r >> 16);
}

__device__ __forceinline__ float fast_tanh(float z) {
    float e = __expf(2.0f * fabsf(z));
    float r = 1.0f - 2.0f / (e + 1.0f);
    return copysignf(r, z);
}

#define AGLD(p)    __hip_atomic_load((p),  __ATOMIC_RELAXED, __HIP_MEMORY_SCOPE_AGENT)
#define AGST(p, v) __hip_atomic_store((p), (v), __ATOMIC_RELAXED, __HIP_MEMORY_SCOPE_AGENT)

__global__ __launch_bounds__(512, 2) void rnn_steps_kernel(
    const float* __restrict__ xs, const float* __restrict__ W1x,
    const float* __restrict__ W1h, const float* __restrict__ b1,
    short* __restrict__ Hbuf, int* __restrict__ flags)
{
    const int gm  = blockIdx.x;   // 0..7 row group
    const int gn  = blockIdx.y;   // 0..7 col block
    const int tid = threadIdx.x;  // 0..511
    const int wv  = tid >> 6;     // wave 0..7 -> 16-col tile
    const int l   = tid & 63;
    const int lr  = l & 15;
    const int q   = l >> 4;       // MFMA k-quad

    const int r0 = gm * MR;             // group's batch rows
    const int cw = gn * NC + wv * 16;   // this wave's 16 cols

    __shared__ short HB[HB_SHORTS];     // staged h slab, B-fragment layout

    // ---- W1h / W1x A-fragments, register-resident (loop-invariant) ----
    // A[m=lr][k=q*8+j] = W[k][cw+lr]  (R3-proven layout)
    shortx8 wh[32], wx[8];
    #pragma unroll
    for (int ks = 0; ks < 32; ++ks) {
        shortx8 f;
        #pragma unroll
        for (int j = 0; j < 8; ++j)
            f[j] = f2bf(W1h[(size_t)(ks * 32 + q * 8 + j) * DH + cw + lr]);
        wh[ks] = f;
    }
    #pragma unroll
    for (int ks = 0; ks < 8; ++ks) {
        shortx8 f;
        #pragma unroll
        for (int j = 0; j < 8; ++j)
            f[j] = f2bf(W1x[(size_t)(ks * 32 + q * 8 + j) * DH + cw + lr]);
        wx[ks] = f;
    }

    floatx4 bias;
    #pragma unroll
    for (int r = 0; r < 4; ++r) bias[r] = b1[cw + q * 4 + r];

    // slab staging decode: chunk c = tid + 512*j -> col4 const, row = base+2j
    const int col4    = tid & 255;            // u64 = 4 cols
    const int sks     = col4 >> 3;
    const int sq      = (col4 >> 1) & 3;
    const int wbase   = sks * S_KS + sq * S_Q + (col4 & 1) * 4;
    const int rowbase = tid >> 8;             // 0..1

    int* const fbase = flags + gm * 8;        // 8 producer blocks per group

    for (int t = 1; t <= TT; ++t) {
        int fv = 0;
        if (t > 1) fv = AGLD(&fbase[l & 7]);  // prime poll early

        floatx4 acc0 = {0.f, 0.f, 0.f, 0.f}, acc1 = {0.f, 0.f, 0.f, 0.f};

        // ---- x_t @ W1x (both row-tiles): independent of h, overlaps flags ----
        #pragma unroll
        for (int rt = 0; rt < 2; ++rt) {
            const float* xrow =
                xs + ((size_t)(t - 1) * BB + r0 + rt * 16 + lr) * DIN + q * 8;
            #pragma unroll
            for (int ks = 0; ks < 8; ++ks) {
                floatx4 x0 = *(const floatx4*)(xrow + ks * 32);
                floatx4 x1 = *(const floatx4*)(xrow + ks * 32 + 4);
                shortx8 b;
                b[0] = f2bf(x0[0]); b[1] = f2bf(x0[1]); b[2] = f2bf(x0[2]); b[3] = f2bf(x0[3]);
                b[4] = f2bf(x1[0]); b[5] = f2bf(x1[1]); b[6] = f2bf(x1[2]); b[7] = f2bf(x1[3]);
                if (rt == 0) acc0 = __builtin_amdgcn_mfma_f32_16x16x32_bf16(wx[ks], b, acc0, 0, 0, 0);
                else         acc1 = __builtin_amdgcn_mfma_f32_16x16x32_bf16(wx[ks], b, acc1, 0, 0, 0);
            }
        }

        // ---- h_{t-1} @ W1h via LDS-staged slab ----
        if (t > 1) {
            while (!__all(fv >= t - 1)) {
                __builtin_amdgcn_s_sleep(1);
                fv = AGLD(&fbase[l & 7]);
            }
            // cooperative stage: 16 u64 agent-loads/thread, ONE batched exposure
            const u64* slab =
                (const u64*)(Hbuf + ((size_t)((t - 1) & 1) * BB + r0) * DH);
            u64 v[16];
            #pragma unroll
            for (int j = 0; j < 16; ++j) v[j] = AGLD(&slab[tid + 512 * j]);
            #pragma unroll
            for (int j = 0; j < 16; ++j) {
                const int row = rowbase + 2 * j;   // 0..31
                *(u64*)&HB[wbase + (row >> 4) * S_RT + (row & 15) * S_LR] = v[j];
            }
            __syncthreads();   // slab visible to all waves

            #pragma unroll
            for (int ks = 0; ks < 32; ++ks) {
                const int fb = ks * S_KS + q * S_Q + lr * S_LR;
                shortx8 b0 = *(const shortx8*)&HB[fb];          // rt=0
                shortx8 b1f = *(const shortx8*)&HB[fb + S_RT];  // rt=1
                acc0 = __builtin_amdgcn_mfma_f32_16x16x32_bf16(wh[ks], b0,  acc0, 0, 0, 0);
                acc1 = __builtin_amdgcn_mfma_f32_16x16x32_bf16(wh[ks], b1f, acc1, 0, 0, 0);
            }
        }

        // ---- tanh, pack, one 8B coherent store per row-tile ----
        {
            short* hp = Hbuf + ((size_t)(t & 1) * BB + r0) * DH + cw + q * 4;
            u64 p0 = 0, p1 = 0;
            #pragma unroll
            for (int r = 0; r < 4; ++r) {
                p0 |= ((u64)(unsigned short)f2bf(fast_tanh(acc0[r] + bias[r]))) << (16 * r);
                p1 |= ((u64)(unsigned short)f2bf(fast_tanh(acc1[r] + bias[r]))) << (16 * r);
            }
            AGST((u64*)(hp + (size_t)(0 * 16 + lr) * DH), p0);
            AGST((u64*)(hp + (size_t)(1 * 16 + lr) * DH), p1);
        }
        // barrier: compiler emits s_waitcnt vmcnt(0) per wave before s_barrier,
        // so ALL waves' coherent stores are drained before the flag post.
        // Also protects HB: every wave is past its ds_reads before next step's
        // staging writes.
        __syncthreads();
        if (tid == 0) AGST(&fbase[gn], t);
    }
}

// out[b][o] = sum_k h[b][k] * W2[k][o] + b2 ; final h in parity-0 buffer.
__global__ __launch_bounds__(256) void readout_kernel(
    const short* __restrict__ Hfin, const float* __restrict__ W2,
    const float* __restrict__ b2, float* __restrict__ out)
{
    const int o  = threadIdx.x;
    const int b0 = blockIdx.x * 4;
    const unsigned* h0 = (const unsigned*)(Hfin + (size_t)(b0 + 0) * DH);
    const unsigned* h1 = (const unsigned*)(Hfin + (size_t)(b0 + 1) * DH);
    const unsigned* h2 = (const unsigned*)(Hfin + (size_t)(b0 + 2) * DH);
    const unsigned* h3 = (const unsigned*)(Hfin + (size_t)(b0 + 3) * DH);
    float a0 = 0.f, a1 = 0.f, a2 = 0.f, a3 = 0.f;
    for (int k2 = 0; k2 < DH / 2; ++k2) {
        float w0 = W2[(2 * k2)     * DOUT + o];
        float w1 = W2[(2 * k2 + 1) * DOUT + o];
        unsigned p0 = h0[k2], p1 = h1[k2], p2 = h2[k2], p3 = h3[k2];
        a0 += __builtin_bit_cast(float, p0 << 16) * w0 + __builtin_bit_cast(float, p0 & 0xffff0000u) * w1;
        a1 += __builtin_bit_cast(float, p1 << 16) * w0 + __builtin_bit_cast(float, p1 & 0xffff0000u) * w1;
        a2 += __builtin_bit_cast(float, p2 << 16) * w0 + __builtin_bit_cast(float, p2 & 0xffff0000u) * w1;
        a3 += __builtin_bit_cast(float, p3 << 16) * w0 + __builtin_bit_cast(float, p3 & 0xffff0000u) * w1;
    }
    const float bias = b2[0];
    out[(b0 + 0) * DOUT + o] = a0 + bias;
    out[(b0 + 1) * DOUT + o] = a1 + bias;
    out[(b0 + 2) * DOUT + o] = a2 + bias;
    out[(b0 + 3) * DOUT + o] = a3 + bias;
}

extern "C" void kernel_launch(void* const* d_in, const int* in_sizes, int n_in,
                              void* d_out, int out_size, void* d_ws, size_t ws_size,
                              hipStream_t stream) {
    (void)in_sizes; (void)n_in; (void)out_size; (void)ws_size;
    const float* xs  = (const float*)d_in[0];   // [128,256,256]
    const float* W1x = (const float*)d_in[1];   // [256,1024]
    const float* W1h = (const float*)d_in[2];   // [1024,1024]
    const float* b1  = (const float*)d_in[3];   // [1024]
    const float* W2  = (const float*)d_in[4];   // [1024,256]
    const float* b2  = (const float*)d_in[5];   // scalar
    float* out = (float*)d_out;                 // [256,256]

    // ws: H double buffer (1 MB) + 64 epoch flags.
    // No memset: 0xAA poison reads as negative epochs.
    short* Hbuf = (short*)d_ws;
    int* flags  = (int*)((char*)d_ws + (size_t)2 * BB * DH * sizeof(short));

    rnn_steps_kernel<<<dim3(NGM, NGN), 512, 0, stream>>>(xs, W1x, W1h, b1, Hbuf, flags);
    // t=128 -> parity 0 buffer holds the final h
    readout_kernel<<<dim3(BB / 4), 256, 0, stream>>>(Hbuf, W2, b2, out);
}

// Round 7
// 1395.903 us; speedup vs baseline: 1.1656x; 1.1656x over previous
//
#include <hip/hip_runtime.h>
#include <hip/hip_bf16.h>
#include <math.h>

// Problem constants
#define TT   128   // timesteps
#define BB   256   // batch
#define DIN  256
#define DH   1024
#define DOUT 256

// R3-proven shape: 8 row-groups (32 batch rows) x 32 col-blocks (32 h-cols).
// Block = 128 threads = 2 waves; wave w owns rows w*16..+15, both 16-col
// tiles. 512 blocks, 64KB LDS -> 2 blocks/CU resident (all co-resident; a
// group only waits on itself). Sync: per-producer-wave epoch flags, lane-
// parallel poll, agent-scope atomics only, zero in-loop barriers (R3-proven).
// R7 change: h B-fragment loads are chunk-pipelined (4 chunks of 8 frags,
// 2 in flight = 64 VGPRs peak) so the allocator keeps them resident and the
// load phase costs ~2 fabric RTTs instead of R3's ~8 collapsed exposures.
#define NGM 8
#define MR  32
#define NGN 32
#define NC  32

typedef float  floatx4 __attribute__((ext_vector_type(4)));
typedef short  shortx8 __attribute__((ext_vector_type(8)));
typedef unsigned long long u64;

__device__ __forceinline__ short f2bf(float f) {
    union { float f; unsigned u; } v; v.f = f;
    unsigned r = v.u + 0x7fffu + ((v.u >> 16) & 1u);   // RNE, inputs never NaN
    return (short)(r >> 16);
}

__device__ __forceinline__ shortx8 mk8(u64 lo, u64 hi) {
    union { struct { u64 a, b; } s; shortx8 v; } u;
    u.s.a = lo; u.s.b = hi;
    return u.v;
}

__device__ __forceinline__ float fast_tanh(float z) {
    float e = __expf(2.0f * fabsf(z));
    float r = 1.0f - 2.0f / (e + 1.0f);
    return copysignf(r, z);
}

#define AGLD(p)    __hip_atomic_load((p),  __ATOMIC_RELAXED, __HIP_MEMORY_SCOPE_AGENT)
#define AGST(p, v) __hip_atomic_store((p), (v), __ATOMIC_RELAXED, __HIP_MEMORY_SCOPE_AGENT)

// issue one 8-frag chunk (16 independent agent loads, stays in 32 VGPRs)
#define LOADC(lo, hi, base) do { \
    _Pragma("unroll") \
    for (int _k = 0; _k < 8; ++_k) { \
        lo[_k] = AGLD((const u64*)(hrow + ((base) + _k) * 32)); \
        hi[_k] = AGLD((const u64*)(hrow + ((base) + _k) * 32 + 4)); \
    } } while (0)
// consume one chunk: 16 MFMAs against LDS-resident W fragments
#define CONSUME(lo, hi, base) do { \
    _Pragma("unroll") \
    for (int _k = 0; _k < 8; ++_k) { \
        shortx8 bfr = mk8(lo[_k], hi[_k]); \
        shortx8 a0 = *(const shortx8*)&WhL[(base) + _k][0][q][lr][0]; \
        shortx8 a1 = *(const shortx8*)&WhL[(base) + _k][1][q][lr][0]; \
        acc0 = __builtin_amdgcn_mfma_f32_16x16x32_bf16(a0, bfr, acc0, 0, 0, 0); \
        acc1 = __builtin_amdgcn_mfma_f32_16x16x32_bf16(a1, bfr, acc1, 0, 0, 0); \
    } } while (0)

__global__ __launch_bounds__(128, 1) void rnn_steps_kernel(
    const float* __restrict__ xs, const float* __restrict__ W1x,
    const float* __restrict__ W1h, const float* __restrict__ b1,
    short* __restrict__ Hbuf, int* __restrict__ flags)
{
    const int gm  = blockIdx.x;   // 0..7 row group
    const int gn  = blockIdx.y;   // 0..31 col block
    const int tid = threadIdx.x;
    const int w   = tid >> 6;     // wave -> 16-row half
    const int l   = tid & 63;
    const int lr  = l & 15;
    const int q   = l >> 4;       // MFMA k-quad

    const int r0 = gm * MR;
    const int c0 = gn * NC;

    // W1h slice as MFMA A-fragments: [kstep][coltile][quad][col][8k] (R3-proven)
    __shared__ short WhL[DH / 32][2][4][16][8];   // 64 KB

    for (int idx = tid; idx < (DH / 32) * 2 * 4 * 16; idx += 128) {
        const int c  = idx & 15;
        const int qq = (idx >> 4) & 3;
        const int ct = (idx >> 6) & 1;
        const int ks = idx >> 7;
        const int col = c0 + ct * 16 + c;
        const int kb  = ks * 32 + qq * 8;
        shortx8 f;
        #pragma unroll
        for (int j = 0; j < 8; ++j) f[j] = f2bf(W1h[(size_t)(kb + j) * DH + col]);
        *(shortx8*)&WhL[ks][ct][qq][c][0] = f;
    }

    // W1x A-fragments register-resident (32 VGPRs)
    shortx8 wx[2][8];
    #pragma unroll
    for (int ct = 0; ct < 2; ++ct)
        #pragma unroll
        for (int ks = 0; ks < 8; ++ks) {
            const int col = c0 + ct * 16 + lr;
            const int kb  = ks * 32 + q * 8;
            shortx8 f;
            #pragma unroll
            for (int j = 0; j < 8; ++j) f[j] = f2bf(W1x[(size_t)(kb + j) * DH + col]);
            wx[ct][ks] = f;
        }
    __syncthreads();   // WhL ready; no barriers after this point

    floatx4 bias[2];
    #pragma unroll
    for (int ct = 0; ct < 2; ++ct)
        #pragma unroll
        for (int r = 0; r < 4; ++r) bias[ct][r] = b1[c0 + ct * 16 + q * 4 + r];

    const int myrow   = r0 + w * 16 + lr;
    int* const fbase  = flags + gm * 64;     // 64 producer-waves per group
    const int  myflag = gn * 2 + w;

    for (int t = 1; t <= TT; ++t) {
        int fv = 0;
        if (t > 1) fv = AGLD(&fbase[l]);     // prime poll early

        floatx4 acc0 = {0.f, 0.f, 0.f, 0.f}, acc1 = {0.f, 0.f, 0.f, 0.f};

        // ---- x_t @ W1x: independent of h, overlaps flag propagation ----
        {
            const float* xrow = xs + ((size_t)(t - 1) * BB + myrow) * DIN + q * 8;
            #pragma unroll
            for (int ks = 0; ks < 8; ++ks) {
                floatx4 x0 = *(const floatx4*)(xrow + ks * 32);
                floatx4 x1 = *(const floatx4*)(xrow + ks * 32 + 4);
                shortx8 b;
                b[0] = f2bf(x0[0]); b[1] = f2bf(x0[1]); b[2] = f2bf(x0[2]); b[3] = f2bf(x0[3]);
                b[4] = f2bf(x1[0]); b[5] = f2bf(x1[1]); b[6] = f2bf(x1[2]); b[7] = f2bf(x1[3]);
                acc0 = __builtin_amdgcn_mfma_f32_16x16x32_bf16(wx[0][ks], b, acc0, 0, 0, 0);
                acc1 = __builtin_amdgcn_mfma_f32_16x16x32_bf16(wx[1][ks], b, acc1, 0, 0, 0);
            }
        }

        // ---- h_{t-1} @ W1h: chunk-pipelined coherent loads ----
        if (t > 1) {
            // lane L polls producer-wave L's epoch (one load covers all 64)
            while (!__all(fv >= t - 1)) {
                __builtin_amdgcn_s_sleep(1);
                fv = AGLD(&fbase[l]);
            }
            const short* hrow = Hbuf + ((size_t)((t - 1) & 1) * BB + myrow) * DH + q * 8;
            u64 alo[8], ahi[8], blo[8], bhi[8];   // 2 chunks in flight, 64 VGPRs
            LOADC(alo, ahi, 0);
            LOADC(blo, bhi, 8);
            CONSUME(alo, ahi, 0);
            LOADC(alo, ahi, 16);
            CONSUME(blo, bhi, 8);
            LOADC(blo, bhi, 24);
            CONSUME(alo, ahi, 16);
            CONSUME(blo, bhi, 24);
        }

        // ---- tanh, pack, two 8B coherent stores (4 contiguous cols each) ----
        {
            short* hp = Hbuf + ((size_t)(t & 1) * BB + myrow) * DH;
            u64 p0 = 0, p1 = 0;
            #pragma unroll
            for (int r = 0; r < 4; ++r) {
                float v0 = fast_tanh(acc0[r] + bias[0][r]);
                float v1 = fast_tanh(acc1[r] + bias[1][r]);
                p0 |= ((u64)(unsigned short)f2bf(v0)) << (16 * r);
                p1 |= ((u64)(unsigned short)f2bf(v1)) << (16 * r);
            }
            AGST((u64*)(hp + c0 + q * 4), p0);
            AGST((u64*)(hp + c0 + 16 + q * 4), p1);
        }
        // drain this wave's stores to the coherence point, then post epoch t
        asm volatile("s_waitcnt vmcnt(0)" ::: "memory");
        AGST(&fbase[myflag], t);
    }
}

// out[b][o] = sum_k h[b][k] * W2[k][o] + b2 ; final h in parity-0 buffer.
__global__ __launch_bounds__(256) void readout_kernel(
    const short* __restrict__ Hfin, const float* __restrict__ W2,
    const float* __restrict__ b2, float* __restrict__ out)
{
    const int o  = threadIdx.x;
    const int b0 = blockIdx.x * 4;
    const unsigned* h0 = (const unsigned*)(Hfin + (size_t)(b0 + 0) * DH);
    const unsigned* h1 = (const unsigned*)(Hfin + (size_t)(b0 + 1) * DH);
    const unsigned* h2 = (const unsigned*)(Hfin + (size_t)(b0 + 2) * DH);
    const unsigned* h3 = (const unsigned*)(Hfin + (size_t)(b0 + 3) * DH);
    float a0 = 0.f, a1 = 0.f, a2 = 0.f, a3 = 0.f;
    for (int k2 = 0; k2 < DH / 2; ++k2) {
        float w0 = W2[(2 * k2)     * DOUT + o];
        float w1 = W2[(2 * k2 + 1) * DOUT + o];
        unsigned p0 = h0[k2], p1 = h1[k2], p2 = h2[k2], p3 = h3[k2];
        a0 += __builtin_bit_cast(float, p0 << 16) * w0 + __builtin_bit_cast(float, p0 & 0xffff0000u) * w1;
        a1 += __builtin_bit_cast(float, p1 << 16) * w0 + __builtin_bit_cast(float, p1 & 0xffff0000u) * w1;
        a2 += __builtin_bit_cast(float, p2 << 16) * w0 + __builtin_bit_cast(float, p2 & 0xffff0000u) * w1;
        a3 += __builtin_bit_cast(float, p3 << 16) * w0 + __builtin_bit_cast(float, p3 & 0xffff0000u) * w1;
    }
    const float bias = b2[0];
    out[(b0 + 0) * DOUT + o] = a0 + bias;
    out[(b0 + 1) * DOUT + o] = a1 + bias;
    out[(b0 + 2) * DOUT + o] = a2 + bias;
    out[(b0 + 3) * DOUT + o] = a3 + bias;
}

extern "C" void kernel_launch(void* const* d_in, const int* in_sizes, int n_in,
                              void* d_out, int out_size, void* d_ws, size_t ws_size,
                              hipStream_t stream) {
    (void)in_sizes; (void)n_in; (void)out_size; (void)ws_size;
    const float* xs  = (const float*)d_in[0];   // [128,256,256]
    const float* W1x = (const float*)d_in[1];   // [256,1024]
    const float* W1h = (const float*)d_in[2];   // [1024,1024]
    const float* b1  = (const float*)d_in[3];   // [1024]
    const float* W2  = (const float*)d_in[4];   // [1024,256]
    const float* b2  = (const float*)d_in[5];   // scalar
    float* out = (float*)d_out;                 // [256,256]

    // ws: H double buffer (1 MB) + 512 epoch flags.
    // No memset: 0xAA poison reads as negative epochs.
    short* Hbuf = (short*)d_ws;
    int* flags  = (int*)((char*)d_ws + (size_t)2 * BB * DH * sizeof(short));

    rnn_steps_kernel<<<dim3(NGM, NGN), 128, 0, stream>>>(xs, W1x, W1h, b1, Hbuf, flags);
    // t=128 -> parity 0 buffer holds the final h
    readout_kernel<<<dim3(BB / 4), 256, 0, stream>>>(Hbuf, W2, b2, out);
}

// Round 9
// 1175.491 us; speedup vs baseline: 1.3842x; 1.1875x over previous
//
#include <hip/hip_runtime.h>
#include <hip/hip_bf16.h>
#include <math.h>

// Problem constants
#define TT   128   // timesteps
#define BB   256   // batch
#define DIN  256
#define DH   1024
#define DOUT 256

// R3-proven shape: 8 row-groups (32 batch rows) x 32 col-blocks (32 h-cols),
// 128 threads (2 waves), 512 blocks, 64KB LDS -> 2 blocks/CU, all co-resident.
//
// R9: FLAGLESS sync. Each bf16 h-value donates its LSB as an epoch bit; each
// 8B word (4 values, written by ONE 8B agent store -> internally consistent)
// carries t mod 16. Consumers load h and validate codes per word; mismatch ->
// reload. No producer drain, no flag post, no poll: the data load IS the
// synchronization. WAR on parity buffers stays safe: h_t fully valid implies
// every wave finished reading h_{t-1} (its stores depend on all its reads).
// Stale parity data differs by 2 mod 16 -> detected; 0xAA poison -> code 0,
// expected 1 at t=2 -> detected; no memset needed.
// Precision: h is effectively bf15 (RNE to the epoch-constrained grid).
#define NGM 8
#define MR  32
#define NGN 32
#define NC  32

typedef float  floatx4 __attribute__((ext_vector_type(4)));
typedef short  shortx8 __attribute__((ext_vector_type(8)));
typedef unsigned long long u64;

#define CMASK 0x0001000100010001ULL

__device__ __forceinline__ short f2bf(float f) {
    union { float f; unsigned u; } v; v.f = f;
    unsigned r = v.u + 0x7fffu + ((v.u >> 16) & 1u);   // RNE, inputs never NaN
    return (short)(r >> 16);
}

// RNE to the bf16 grid restricted to LSB==bit (step 2 ulp): error <= 1 ulp bf16
__device__ __forceinline__ unsigned short bf15e(float v, unsigned bit) {
    union { float f; unsigned u; } x; x.f = v;
    unsigned ua = x.u - (bit << 16);
    unsigned k  = (ua + 0xFFFFu + ((ua >> 17) & 1u)) >> 17;
    return (unsigned short)((k << 1) | bit);
}

__device__ __forceinline__ shortx8 mk8(u64 lo, u64 hi) {
    union { struct { u64 a, b; } s; shortx8 v; } u;
    u.s.a = lo; u.s.b = hi;
    return u.v;
}

__device__ __forceinline__ float fast_tanh(float z) {
    float e = __expf(2.0f * fabsf(z));
    float r = 1.0f - 2.0f / (e + 1.0f);
    return copysignf(r, z);
}

#define AGLD(p)    __hip_atomic_load((p),  __ATOMIC_RELAXED, __HIP_MEMORY_SCOPE_AGENT)
#define AGST(p, v) __hip_atomic_store((p), (v), __ATOMIC_RELAXED, __HIP_MEMORY_SCOPE_AGENT)

// load one 8-ks chunk: 16 u64 (R7-proven 32-VGPR buffer)
#define LD16(buf, base) do { \
    _Pragma("unroll") \
    for (int _j = 0; _j < 8; ++_j) { \
        buf[2 * _j]     = AGLD((const u64*)(hrow + ((base) + _j) * 32)); \
        buf[2 * _j + 1] = AGLD((const u64*)(hrow + ((base) + _j) * 32 + 4)); \
    } } while (0)
// per-word epoch validation, wave-wide verdict
#define OK16(buf, okvar) do { \
    int _o = 1; \
    _Pragma("unroll") \
    for (int _j = 0; _j < 16; ++_j) _o &= ((buf[_j] & CMASK) == pat); \
    okvar = __all(_o); } while (0)
#define WAITVALID(buf, base) do { \
    int _okk; OK16(buf, _okk); \
    while (!_okk) { LD16(buf, base); OK16(buf, _okk); } } while (0)
#define CONS16(buf, base) do { \
    _Pragma("unroll") \
    for (int _j = 0; _j < 8; ++_j) { \
        shortx8 bfr = mk8(buf[2 * _j], buf[2 * _j + 1]); \
        shortx8 a0 = *(const shortx8*)&WhL[(base) + _j][0][q][lr][0]; \
        shortx8 a1 = *(const shortx8*)&WhL[(base) + _j][1][q][lr][0]; \
        acc0 = __builtin_amdgcn_mfma_f32_16x16x32_bf16(a0, bfr, acc0, 0, 0, 0); \
        acc1 = __builtin_amdgcn_mfma_f32_16x16x32_bf16(a1, bfr, acc1, 0, 0, 0); \
    } } while (0)

__global__ __launch_bounds__(128, 1) void rnn_steps_kernel(
    const float* __restrict__ xs, const float* __restrict__ W1x,
    const float* __restrict__ W1h, const float* __restrict__ b1,
    short* __restrict__ Hbuf)
{
    const int gm  = blockIdx.x;   // 0..7 row group
    const int gn  = blockIdx.y;   // 0..31 col block
    const int tid = threadIdx.x;
    const int w   = tid >> 6;     // wave -> 16-row half
    const int l   = tid & 63;
    const int lr  = l & 15;
    const int q   = l >> 4;       // MFMA k-quad

    const int r0 = gm * MR;
    const int c0 = gn * NC;

    // W1h slice as MFMA A-fragments in LDS (R3-proven layout)
    __shared__ short WhL[DH / 32][2][4][16][8];   // 64 KB
    for (int idx = tid; idx < (DH / 32) * 2 * 4 * 16; idx += 128) {
        const int c  = idx & 15;
        const int qq = (idx >> 4) & 3;
        const int ct = (idx >> 6) & 1;
        const int ks = idx >> 7;
        shortx8 f;
        #pragma unroll
        for (int j = 0; j < 8; ++j)
            f[j] = f2bf(W1h[(size_t)(ks * 32 + qq * 8 + j) * DH + c0 + ct * 16 + c]);
        *(shortx8*)&WhL[ks][ct][qq][c][0] = f;
    }
    // W1x A-fragments register-resident (32 VGPRs)
    shortx8 wx[2][8];
    #pragma unroll
    for (int ct = 0; ct < 2; ++ct)
        #pragma unroll
        for (int ks = 0; ks < 8; ++ks) {
            shortx8 f;
            #pragma unroll
            for (int j = 0; j < 8; ++j)
                f[j] = f2bf(W1x[(size_t)(ks * 32 + q * 8 + j) * DH + c0 + ct * 16 + lr]);
            wx[ct][ks] = f;
        }
    __syncthreads();   // WhL ready; no barriers after this point

    floatx4 bias[2];
    #pragma unroll
    for (int ct = 0; ct < 2; ++ct)
        #pragma unroll
        for (int r = 0; r < 4; ++r) bias[ct][r] = b1[c0 + ct * 16 + q * 4 + r];

    const int myrow = r0 + w * 16 + lr;
    const size_t HS = (size_t)BB * DH;

    for (int t = 1; t <= TT; ++t) {
        const short* const hrow =
            Hbuf + (size_t)((t - 1) & 1) * HS + (size_t)myrow * DH + q * 8;
        // expected epoch pattern for h_{t-1}: bit r of (t-1)&15 in halfword r
        const unsigned e = (unsigned)(t - 1) & 15u;
        const u64 pat = ((u64)(e & 1u)) | ((u64)((e >> 1) & 1u) << 16) |
                        ((u64)((e >> 2) & 1u) << 32) | ((u64)((e >> 3) & 1u) << 48);

        u64 A[16], B[16];
        if (t > 1) LD16(A, 0);   // early prefetch; validated later, self-correcting

        floatx4 acc0 = {0.f, 0.f, 0.f, 0.f}, acc1 = {0.f, 0.f, 0.f, 0.f};

        // ---- x_t @ W1x: independent of h, hides the first h-load RTT ----
        {
            const float* xrow = xs + ((size_t)(t - 1) * BB + myrow) * DIN + q * 8;
            #pragma unroll
            for (int ks = 0; ks < 8; ++ks) {
                floatx4 x0 = *(const floatx4*)(xrow + ks * 32);
                floatx4 x1 = *(const floatx4*)(xrow + ks * 32 + 4);
                shortx8 b;
                b[0] = f2bf(x0[0]); b[1] = f2bf(x0[1]); b[2] = f2bf(x0[2]); b[3] = f2bf(x0[3]);
                b[4] = f2bf(x1[0]); b[5] = f2bf(x1[1]); b[6] = f2bf(x1[2]); b[7] = f2bf(x1[3]);
                acc0 = __builtin_amdgcn_mfma_f32_16x16x32_bf16(wx[0][ks], b, acc0, 0, 0, 0);
                acc1 = __builtin_amdgcn_mfma_f32_16x16x32_bf16(wx[1][ks], b, acc1, 0, 0, 0);
            }
        }

        // ---- h_{t-1} @ W1h: self-validating chunk-pipelined loads ----
        if (t > 1) {
            LD16(B, 8);
            WAITVALID(A, 0);
            CONS16(A, 0);
            LD16(A, 16);
            WAITVALID(B, 8);
            CONS16(B, 8);
            LD16(B, 24);
            WAITVALID(A, 16);
            CONS16(A, 16);
            WAITVALID(B, 24);
            CONS16(B, 24);
        }

        // ---- tanh, encode epoch bits, two 8B stores (fire-and-forget) ----
        {
            short* hp = Hbuf + (size_t)(t & 1) * HS + (size_t)myrow * DH + c0 + q * 4;
            u64 p0 = 0, p1 = 0;
            #pragma unroll
            for (int r = 0; r < 4; ++r) {
                const unsigned bit = ((unsigned)t >> r) & 1u;
                p0 |= ((u64)bf15e(fast_tanh(acc0[r] + bias[0][r]), bit)) << (16 * r);
                p1 |= ((u64)bf15e(fast_tanh(acc1[r] + bias[1][r]), bit)) << (16 * r);
            }
            AGST((u64*)(hp), p0);
            AGST((u64*)(hp + 16), p1);
            // no drain, no flag: each 8B word is self-validating at consumers
        }
    }
    // end-of-kernel release makes final H visible to readout_kernel
}

// out[b][o] = sum_k h[b][k] * W2[k][o] + b2 ; final h in parity-0 buffer
// (t=128 -> epoch code 0 -> stored LSBs are all zero, clean bf15 values).
__global__ __launch_bounds__(256) void readout_kernel(
    const short* __restrict__ Hfin, const float* __restrict__ W2,
    const float* __restrict__ b2, float* __restrict__ out)
{
    const int o  = threadIdx.x;
    const int b0 = blockIdx.x * 4;
    const unsigned* h0 = (const unsigned*)(Hfin + (size_t)(b0 + 0) * DH);
    const unsigned* h1 = (const unsigned*)(Hfin + (size_t)(b0 + 1) * DH);
    const unsigned* h2 = (const unsigned*)(Hfin + (size_t)(b0 + 2) * DH);
    const unsigned* h3 = (const unsigned*)(Hfin + (size_t)(b0 + 3) * DH);
    float a0 = 0.f, a1 = 0.f, a2 = 0.f, a3 = 0.f;
    for (int k2 = 0; k2 < DH / 2; ++k2) {
        float w0 = W2[(2 * k2)     * DOUT + o];
        float w1 = W2[(2 * k2 + 1) * DOUT + o];
        unsigned p0 = h0[k2], p1 = h1[k2], p2 = h2[k2], p3 = h3[k2];
        a0 += __builtin_bit_cast(float, p0 << 16) * w0 + __builtin_bit_cast(float, p0 & 0xffff0000u) * w1;
        a1 += __builtin_bit_cast(float, p1 << 16) * w0 + __builtin_bit_cast(float, p1 & 0xffff0000u) * w1;
        a2 += __builtin_bit_cast(float, p2 << 16) * w0 + __builtin_bit_cast(float, p2 & 0xffff0000u) * w1;
        a3 += __builtin_bit_cast(float, p3 << 16) * w0 + __builtin_bit_cast(float, p3 & 0xffff0000u) * w1;
    }
    const float bias = b2[0];
    out[(b0 + 0) * DOUT + o] = a0 + bias;
    out[(b0 + 1) * DOUT + o] = a1 + bias;
    out[(b0 + 2) * DOUT + o] = a2 + bias;
    out[(b0 + 3) * DOUT + o] = a3 + bias;
}

extern "C" void kernel_launch(void* const* d_in, const int* in_sizes, int n_in,
                              void* d_out, int out_size, void* d_ws, size_t ws_size,
                              hipStream_t stream) {
    (void)in_sizes; (void)n_in; (void)out_size; (void)ws_size;
    const float* xs  = (const float*)d_in[0];   // [128,256,256]
    const float* W1x = (const float*)d_in[1];   // [256,1024]
    const float* W1h = (const float*)d_in[2];   // [1024,1024]
    const float* b1  = (const float*)d_in[3];   // [1024]
    const float* W2  = (const float*)d_in[4];   // [1024,256]
    const float* b2  = (const float*)d_in[5];   // scalar
    float* out = (float*)d_out;                 // [256,256]

    // ws: H parity double buffer only (1 MB). No flags, no memset:
    // 0xAA poison decodes as epoch 0, which never matches the first expected
    // epoch (1) -> consumers treat it as not-yet-written and retry.
    short* Hbuf = (short*)d_ws;

    rnn_steps_kernel<<<dim3(NGM, NGN), 128, 0, stream>>>(xs, W1x, W1h, b1, Hbuf);
    // t=128 -> parity 0 buffer holds the final h
    readout_kernel<<<dim3(BB / 4), 256, 0, stream>>>(Hbuf, W2, b2, out);
}

// Round 10
// 1141.239 us; speedup vs baseline: 1.4258x; 1.0300x over previous
//
#include <hip/hip_runtime.h>
#include <hip/hip_bf16.h>
#include <math.h>

// Problem constants
#define TT   128
#define BB   256
#define DIN  256
#define DH   1024
#define DOUT 256

// R3-proven shape: 8 row-groups (32 rows) x 32 col-blocks (32 cols), 128 thr.
//
// R10: plain-cached fan-out. Producers AGST h (through to MALL, proven) and
// post R3-proven epoch flags (AGST after vmcnt(0) drain). Consumers poll
// flags (AGLD, lane-parallel), then read h with PLAIN 16B loads into a
// 63-deep version ring: addresses virgin for 63 steps -> L1/L2 miss -> fill
// fresh from MALL; the filled line then serves the other 31 blocks of the
// group from the XCD's L2 (the fan-out stops hammering the fabric).
// Safety net (proven, R9): every bf16 h value donates its LSB; each 8B word
// carries code(t)=1+((t-1)%15) (never 0 = poison; 63%15=3 so ring-stale
// codes never alias). Any stale L1/L2 hit is detected and retried via AGLD.
// ws too small for the ring -> exact R9 fallback (M=2, AGLD-only, flagless).
#define NGM 8
#define MR  32
#define NGN 32
#define NC  32

typedef float  floatx4 __attribute__((ext_vector_type(4)));
typedef short  shortx8 __attribute__((ext_vector_type(8)));
typedef unsigned long long u64;

#define CMASK 0x0001000100010001ULL

__device__ __forceinline__ short f2bf(float f) {
    union { float f; unsigned u; } v; v.f = f;
    unsigned r = v.u + 0x7fffu + ((v.u >> 16) & 1u);   // RNE, inputs never NaN
    return (short)(r >> 16);
}

// RNE to the bf16 grid restricted to LSB==bit (step 2 ulp): err <= 1 ulp bf16
__device__ __forceinline__ unsigned short bf15e(float v, unsigned bit) {
    union { float f; unsigned u; } x; x.f = v;
    unsigned ua = x.u - (bit << 16);
    unsigned k  = (ua + 0xFFFFu + ((ua >> 17) & 1u)) >> 17;
    return (unsigned short)((k << 1) | bit);
}

__device__ __forceinline__ shortx8 mk8(u64 lo, u64 hi) {
    union { struct { u64 a, b; } s; shortx8 v; } u;
    u.s.a = lo; u.s.b = hi;
    return u.v;
}

__device__ __forceinline__ float fast_tanh(float z) {
    float e = __expf(2.0f * fabsf(z));
    float r = 1.0f - 2.0f / (e + 1.0f);
    return copysignf(r, z);
}

#define AGLD(p)    __hip_atomic_load((p),  __ATOMIC_RELAXED, __HIP_MEMORY_SCOPE_AGENT)
#define AGST(p, v) __hip_atomic_store((p), (v), __ATOMIC_RELAXED, __HIP_MEMORY_SCOPE_AGENT)

// AGLD chunk load (R9-proven; used for fallback first-pass and all retries)
#define LD16(buf, base) do { \
    _Pragma("unroll") \
    for (int _j = 0; _j < 8; ++_j) { \
        buf[2 * _j]     = AGLD((const u64*)(hrow + ((base) + _j) * 32)); \
        buf[2 * _j + 1] = AGLD((const u64*)(hrow + ((base) + _j) * 32 + 4)); \
    } } while (0)
// plain cached 16B first-pass (big path: virgin ring addresses, post-flag)
#define LD16P(buf, base) do { \
    _Pragma("unroll") \
    for (int _j = 0; _j < 8; ++_j) { \
        union { shortx8 s; u64 d[2]; } _u; \
        _u.s = *(const shortx8*)(hrow + ((base) + _j) * 32); \
        buf[2 * _j] = _u.d[0]; buf[2 * _j + 1] = _u.d[1]; \
    } } while (0)
#define OK16(buf, okvar) do { \
    int _o = 1; \
    _Pragma("unroll") \
    for (int _j = 0; _j < 16; ++_j) _o &= ((buf[_j] & CMASK) == pat); \
    okvar = __all(_o); } while (0)
#define WAITVALID(buf, base) do { \
    int _okk; OK16(buf, _okk); \
    while (!_okk) { __builtin_amdgcn_s_sleep(1); LD16(buf, base); OK16(buf, _okk); } \
    } while (0)
#define CONS16(buf, base) do { \
    _Pragma("unroll") \
    for (int _j = 0; _j < 8; ++_j) { \
        shortx8 bfr = mk8(buf[2 * _j], buf[2 * _j + 1]); \
        shortx8 a0 = *(const shortx8*)&WhL[(base) + _j][0][q][lr][0]; \
        shortx8 a1 = *(const shortx8*)&WhL[(base) + _j][1][q][lr][0]; \
        acc0 = __builtin_amdgcn_mfma_f32_16x16x32_bf16(a0, bfr, acc0, 0, 0, 0); \
        acc1 = __builtin_amdgcn_mfma_f32_16x16x32_bf16(a1, bfr, acc1, 0, 0, 0); \
    } } while (0)

__global__ __launch_bounds__(128, 1) void rnn_steps_kernel(
    const float* __restrict__ xs, const float* __restrict__ W1x,
    const float* __restrict__ W1h, const float* __restrict__ b1,
    short* __restrict__ Hbuf, int* __restrict__ flags, int big, int M)
{
    const int gm  = blockIdx.x;
    const int gn  = blockIdx.y;
    const int tid = threadIdx.x;
    const int w   = tid >> 6;
    const int l   = tid & 63;
    const int lr  = l & 15;
    const int q   = l >> 4;

    const int r0 = gm * MR;
    const int c0 = gn * NC;

    __shared__ short WhL[DH / 32][2][4][16][8];   // 64 KB (R3-proven layout)
    for (int idx = tid; idx < (DH / 32) * 2 * 4 * 16; idx += 128) {
        const int c  = idx & 15;
        const int qq = (idx >> 4) & 3;
        const int ct = (idx >> 6) & 1;
        const int ks = idx >> 7;
        shortx8 f;
        #pragma unroll
        for (int j = 0; j < 8; ++j)
            f[j] = f2bf(W1h[(size_t)(ks * 32 + qq * 8 + j) * DH + c0 + ct * 16 + c]);
        *(shortx8*)&WhL[ks][ct][qq][c][0] = f;
    }
    shortx8 wx[2][8];
    #pragma unroll
    for (int ct = 0; ct < 2; ++ct)
        #pragma unroll
        for (int ks = 0; ks < 8; ++ks) {
            shortx8 f;
            #pragma unroll
            for (int j = 0; j < 8; ++j)
                f[j] = f2bf(W1x[(size_t)(ks * 32 + q * 8 + j) * DH + c0 + ct * 16 + lr]);
            wx[ct][ks] = f;
        }
    __syncthreads();   // WhL ready; no barriers after this point

    floatx4 bias[2];
    #pragma unroll
    for (int ct = 0; ct < 2; ++ct)
        #pragma unroll
        for (int r = 0; r < 4; ++r) bias[ct][r] = b1[c0 + ct * 16 + q * 4 + r];

    const int myrow   = r0 + w * 16 + lr;
    const size_t HS   = (size_t)BB * DH;
    int* const fbase  = flags + gm * 64;     // 64 producer-waves per group
    const int  myflag = gn * 2 + w;

    int cc = 1, pc = 0;          // epoch codes: code(t)=1+((t-1)%15), never 0
    int cv = 1 % M, pv = 0;      // version ring: v(t)=t%M  (M=2 -> parity)

    for (int t = 1; t <= TT; ++t) {
        const short* const hrow =
            Hbuf + (size_t)pv * HS + (size_t)myrow * DH + q * 8;
        const u64 pat = ((u64)(pc & 1)) | ((u64)((pc >> 1) & 1) << 16) |
                        ((u64)((pc >> 2) & 1) << 32) | ((u64)((pc >> 3) & 1) << 48);

        u64 A[16], B[16];
        int fv = 0;
        if (t > 1) {
            if (big) fv = AGLD(&fbase[l]);   // prime flag poll
            else     LD16(A, 0);             // R9: early AGLD prefetch
        }

        floatx4 acc0 = {0.f, 0.f, 0.f, 0.f}, acc1 = {0.f, 0.f, 0.f, 0.f};

        // ---- x_t @ W1x: independent of h, hides flag/load latency ----
        {
            const float* xrow = xs + ((size_t)(t - 1) * BB + myrow) * DIN + q * 8;
            #pragma unroll
            for (int ks = 0; ks < 8; ++ks) {
                floatx4 x0 = *(const floatx4*)(xrow + ks * 32);
                floatx4 x1 = *(const floatx4*)(xrow + ks * 32 + 4);
                shortx8 b;
                b[0] = f2bf(x0[0]); b[1] = f2bf(x0[1]); b[2] = f2bf(x0[2]); b[3] = f2bf(x0[3]);
                b[4] = f2bf(x1[0]); b[5] = f2bf(x1[1]); b[6] = f2bf(x1[2]); b[7] = f2bf(x1[3]);
                acc0 = __builtin_amdgcn_mfma_f32_16x16x32_bf16(wx[0][ks], b, acc0, 0, 0, 0);
                acc1 = __builtin_amdgcn_mfma_f32_16x16x32_bf16(wx[1][ks], b, acc1, 0, 0, 0);
            }
        }

        // ---- h_{t-1} @ W1h ----
        if (t > 1) {
            if (big) {
                // R3-proven poll: all 64 producers posted -> data at MALL
                while (!__all(fv >= t - 1)) {
                    __builtin_amdgcn_s_sleep(1);
                    fv = AGLD(&fbase[l]);
                }
                asm volatile("" ::: "memory");   // keep plain loads after poll
                LD16P(A, 0);
                LD16P(B, 8);
                WAITVALID(A, 0);  CONS16(A, 0);
                LD16P(A, 16);
                WAITVALID(B, 8);  CONS16(B, 8);
                LD16P(B, 24);
                WAITVALID(A, 16); CONS16(A, 16);
                WAITVALID(B, 24); CONS16(B, 24);
            } else {
                LD16(B, 8);
                WAITVALID(A, 0);  CONS16(A, 0);
                LD16(A, 16);
                WAITVALID(B, 8);  CONS16(B, 8);
                LD16(B, 24);
                WAITVALID(A, 16); CONS16(A, 16);
                WAITVALID(B, 24); CONS16(B, 24);
            }
        }

        // ---- tanh, encode epoch code cc, two 8B AGSTs ----
        {
            short* hp = Hbuf + (size_t)cv * HS + (size_t)myrow * DH + c0 + q * 4;
            u64 p0 = 0, p1 = 0;
            #pragma unroll
            for (int r = 0; r < 4; ++r) {
                const unsigned bit = ((unsigned)cc >> r) & 1u;
                p0 |= ((u64)bf15e(fast_tanh(acc0[r] + bias[0][r]), bit)) << (16 * r);
                p1 |= ((u64)bf15e(fast_tanh(acc1[r] + bias[1][r]), bit)) << (16 * r);
            }
            AGST((u64*)(hp), p0);
            AGST((u64*)(hp + 16), p1);
            if (big) {   // R3-proven: drain to MALL, then post epoch flag
                asm volatile("s_waitcnt vmcnt(0)" ::: "memory");
                AGST(&fbase[myflag], t);
            }
        }

        pc = cc; cc = (cc == 15) ? 1 : cc + 1;
        pv = cv; cv = (cv + 1 == M) ? 0 : cv + 1;
    }
}

// out[b][o] = sum_k h[b][k]*W2[k][o] + b2. Final h staged via AGLD -> LDS
// (readout's L2 may hold 63-step-stale lines for ring addresses).
__global__ __launch_bounds__(256) void readout_kernel(
    const short* __restrict__ Hfin, const float* __restrict__ W2,
    const float* __restrict__ b2, float* __restrict__ out)
{
    const int o  = threadIdx.x;
    const int b0 = blockIdx.x * 4;
    __shared__ u64 hs8[4 * DH / 4];                 // 4 rows x 1024 bf16 = 8 KB
    const u64* src = (const u64*)(Hfin + (size_t)b0 * DH);
    for (int i = o; i < 4 * DH / 4; i += 256) hs8[i] = AGLD(&src[i]);
    __syncthreads();
    const unsigned* h0 = (const unsigned*)&hs8[0 * DH / 4];
    const unsigned* h1 = (const unsigned*)&hs8[1 * DH / 4];
    const unsigned* h2 = (const unsigned*)&hs8[2 * DH / 4];
    const unsigned* h3 = (const unsigned*)&hs8[3 * DH / 4];
    float a0 = 0.f, a1 = 0.f, a2 = 0.f, a3 = 0.f;
    for (int k2 = 0; k2 < DH / 2; ++k2) {
        float w0 = W2[(2 * k2)     * DOUT + o];
        float w1 = W2[(2 * k2 + 1) * DOUT + o];
        unsigned p0 = h0[k2], p1 = h1[k2], p2 = h2[k2], p3 = h3[k2];
        a0 += __builtin_bit_cast(float, p0 << 16) * w0 + __builtin_bit_cast(float, p0 & 0xffff0000u) * w1;
        a1 += __builtin_bit_cast(float, p1 << 16) * w0 + __builtin_bit_cast(float, p1 & 0xffff0000u) * w1;
        a2 += __builtin_bit_cast(float, p2 << 16) * w0 + __builtin_bit_cast(float, p2 & 0xffff0000u) * w1;
        a3 += __builtin_bit_cast(float, p3 << 16) * w0 + __builtin_bit_cast(float, p3 & 0xffff0000u) * w1;
    }
    const float bias = b2[0];
    out[(b0 + 0) * DOUT + o] = a0 + bias;
    out[(b0 + 1) * DOUT + o] = a1 + bias;
    out[(b0 + 2) * DOUT + o] = a2 + bias;
    out[(b0 + 3) * DOUT + o] = a3 + bias;
}

extern "C" void kernel_launch(void* const* d_in, const int* in_sizes, int n_in,
                              void* d_out, int out_size, void* d_ws, size_t ws_size,
                              hipStream_t stream) {
    (void)in_sizes; (void)n_in; (void)out_size;
    const float* xs  = (const float*)d_in[0];   // [128,256,256]
    const float* W1x = (const float*)d_in[1];   // [256,1024]
    const float* W1h = (const float*)d_in[2];   // [1024,1024]
    const float* b1  = (const float*)d_in[3];   // [1024]
    const float* W2  = (const float*)d_in[4];   // [1024,256]
    const float* b2  = (const float*)d_in[5];   // scalar
    float* out = (float*)d_out;                 // [256,256]

    // big: 63-version ring (31.5 MB) + 512 flag ints. small: R9 parity (1 MB).
    // No memset: poison = negative flags / code-0 words, both handled.
    const size_t HS   = (size_t)BB * DH;                 // shorts per version
    int M = 63, big = 1;
    size_t need = (size_t)M * HS * sizeof(short) + 512 * sizeof(int) + 1024;
    if (ws_size < need) { big = 0; M = 2; }
    short* Hbuf = (short*)d_ws;
    int* flags  = (int*)((char*)d_ws + (size_t)M * HS * sizeof(short));

    rnn_steps_kernel<<<dim3(NGM, NGN), 128, 0, stream>>>(
        xs, W1x, W1h, b1, Hbuf, flags, big, M);
    const short* Hfin = Hbuf + (size_t)(TT % M) * HS;    // h_128
    readout_kernel<<<dim3(BB / 4), 256, 0, stream>>>(Hfin, W2, b2, out);
}

// Round 11
// 753.784 us; speedup vs baseline: 2.1586x; 1.5140x over previous
//
#include <hip/hip_runtime.h>
#include <hip/hip_bf16.h>
#include <math.h>

// Problem constants
#define TT   128
#define BB   256
#define DIN  256
#define DH   1024
#define DOUT 256

// R3-proven shape: 8 row-groups (32 rows) x 32 col-blocks (32 cols), 128 thr,
// 512 blocks, 64KB LDS -> 2/CU co-resident. R9-proven flagless sync (epoch
// bit stolen from each bf16 LSB; every 8B word self-validates; AGLD/AGST
// agent-scope only; no fences, no flags, no barriers in the loop).
//
// R11 change: H lives in MFMA B-FRAGMENT ORDER, not row-major.
//   Hg[group][rt][ks][qq][lr][j]  (shorts; strides 32768/16384/512/128/8/1)
// Consumer lane (q,lr) loads frag ks at q*128+lr*8: consecutive lanes ->
// consecutive addresses -> one coalesced 1KB access per wave instead of 64
// scattered 8B txns (the R3..R10 plateau was ~2M fabric txns/step from the
// 2KB-strided row-major exchange). Producer's 4 acc values = one contiguous
// 8B word in this layout (col = gn*32+qq*8+j == c0+ct*16+q*4+r), so stores
// coalesce too. Epoch-code validation identical to R9 (bits 0..3 in every
// word's 4 halfword-LSBs).
#define NGM 8
#define MR  32
#define NGN 32
#define NC  32

typedef float  floatx4 __attribute__((ext_vector_type(4)));
typedef short  shortx8 __attribute__((ext_vector_type(8)));
typedef unsigned long long u64;

#define CMASK 0x0001000100010001ULL
#define GSTRIDE 32768           // shorts per group slab (2*32*4*16*8)

__device__ __forceinline__ short f2bf(float f) {
    union { float f; unsigned u; } v; v.f = f;
    unsigned r = v.u + 0x7fffu + ((v.u >> 16) & 1u);   // RNE, inputs never NaN
    return (short)(r >> 16);
}

// RNE to the bf16 grid restricted to LSB==bit (step 2 ulp): err <= 1 ulp bf16
__device__ __forceinline__ unsigned short bf15e(float v, unsigned bit) {
    union { float f; unsigned u; } x; x.f = v;
    unsigned ua = x.u - (bit << 16);
    unsigned k  = (ua + 0xFFFFu + ((ua >> 17) & 1u)) >> 17;
    return (unsigned short)((k << 1) | bit);
}

__device__ __forceinline__ shortx8 mk8(u64 lo, u64 hi) {
    union { struct { u64 a, b; } s; shortx8 v; } u;
    u.s.a = lo; u.s.b = hi;
    return u.v;
}

__device__ __forceinline__ float fast_tanh(float z) {
    float e = __expf(2.0f * fabsf(z));
    float r = 1.0f - 2.0f / (e + 1.0f);
    return copysignf(r, z);
}

#define AGLD(p)    __hip_atomic_load((p),  __ATOMIC_RELAXED, __HIP_MEMORY_SCOPE_AGENT)
#define AGST(p, v) __hip_atomic_store((p), (v), __ATOMIC_RELAXED, __HIP_MEMORY_SCOPE_AGENT)

// hfr = group slab base + rt*16384 + q*128 + lr*8 ; frag ks at +ks*512.
// One chunk = 8 ks fragments = 16 u64 AGLDs, COALESCED across lanes.
#define LD16(buf, base) do { \
    _Pragma("unroll") \
    for (int _j = 0; _j < 8; ++_j) { \
        const u64* _p = (const u64*)(hfr + ((base) + _j) * 512); \
        buf[2 * _j]     = AGLD(_p); \
        buf[2 * _j + 1] = AGLD(_p + 1); \
    } } while (0)
#define OK16(buf, okvar) do { \
    int _o = 1; \
    _Pragma("unroll") \
    for (int _j = 0; _j < 16; ++_j) _o &= ((buf[_j] & CMASK) == pat); \
    okvar = __all(_o); } while (0)
#define WAITVALID(buf, base) do { \
    int _okk; OK16(buf, _okk); \
    while (!_okk) { __builtin_amdgcn_s_sleep(1); LD16(buf, base); OK16(buf, _okk); } \
    } while (0)
#define CONS16(buf, base) do { \
    _Pragma("unroll") \
    for (int _j = 0; _j < 8; ++_j) { \
        shortx8 bfr = mk8(buf[2 * _j], buf[2 * _j + 1]); \
        shortx8 a0 = *(const shortx8*)&WhL[(base) + _j][0][q][lr][0]; \
        shortx8 a1 = *(const shortx8*)&WhL[(base) + _j][1][q][lr][0]; \
        acc0 = __builtin_amdgcn_mfma_f32_16x16x32_bf16(a0, bfr, acc0, 0, 0, 0); \
        acc1 = __builtin_amdgcn_mfma_f32_16x16x32_bf16(a1, bfr, acc1, 0, 0, 0); \
    } } while (0)

__global__ __launch_bounds__(128, 1) void rnn_steps_kernel(
    const float* __restrict__ xs, const float* __restrict__ W1x,
    const float* __restrict__ W1h, const float* __restrict__ b1,
    short* __restrict__ Hbuf)
{
    const int gm  = blockIdx.x;   // 0..7 row group
    const int gn  = blockIdx.y;   // 0..31 col block
    const int tid = threadIdx.x;
    const int w   = tid >> 6;     // wave -> 16-row tile
    const int l   = tid & 63;
    const int lr  = l & 15;
    const int q   = l >> 4;       // MFMA k-quad

    const int r0 = gm * MR;
    const int c0 = gn * NC;

    // W1h slice as MFMA A-fragments in LDS (R3-proven layout)
    __shared__ short WhL[DH / 32][2][4][16][8];   // 64 KB
    for (int idx = tid; idx < (DH / 32) * 2 * 4 * 16; idx += 128) {
        const int c  = idx & 15;
        const int qq = (idx >> 4) & 3;
        const int ct = (idx >> 6) & 1;
        const int ks = idx >> 7;
        shortx8 f;
        #pragma unroll
        for (int j = 0; j < 8; ++j)
            f[j] = f2bf(W1h[(size_t)(ks * 32 + qq * 8 + j) * DH + c0 + ct * 16 + c]);
        *(shortx8*)&WhL[ks][ct][qq][c][0] = f;
    }
    // W1x A-fragments register-resident (32 VGPRs)
    shortx8 wx[2][8];
    #pragma unroll
    for (int ct = 0; ct < 2; ++ct)
        #pragma unroll
        for (int ks = 0; ks < 8; ++ks) {
            shortx8 f;
            #pragma unroll
            for (int j = 0; j < 8; ++j)
                f[j] = f2bf(W1x[(size_t)(ks * 32 + q * 8 + j) * DH + c0 + ct * 16 + lr]);
            wx[ct][ks] = f;
        }
    __syncthreads();   // WhL ready; no barriers after this point

    floatx4 bias[2];
    #pragma unroll
    for (int ct = 0; ct < 2; ++ct)
        #pragma unroll
        for (int r = 0; r < 4; ++r) bias[ct][r] = b1[c0 + ct * 16 + q * 4 + r];

    const int myrow = r0 + w * 16 + lr;        // xs rows (unchanged)
    const size_t HS = (size_t)BB * DH;         // shorts per version

    // fragment-layout bases (consumer reads its own row-tile w)
    short* const Hg   = Hbuf + gm * GSTRIDE;
    const int rdoff   = w * 16384 + q * 128 + lr * 8;
    // producer store offsets (ks=gn): [w][gn][ct*2+(q>>1)][lr][(q&1)*4]
    const int wroff   = w * 16384 + gn * 512 + (q >> 1) * 128 + lr * 8 + (q & 1) * 4;

    for (int t = 1; t <= TT; ++t) {
        const short* const hfr = Hg + (size_t)((t - 1) & 1) * HS + rdoff;
        // expected epoch code for h_{t-1}: 1+((t-2)%15) in [1,15]; t=1 unused.
        const int pc = (t >= 2) ? (1 + ((t - 2) % 15)) : 0;
        const u64 pat = ((u64)(pc & 1)) | ((u64)((pc >> 1) & 1) << 16) |
                        ((u64)((pc >> 2) & 1) << 32) | ((u64)((pc >> 3) & 1) << 48);

        u64 A[16], B[16];
        if (t > 1) LD16(A, 0);   // early prefetch; validated later, self-correcting

        floatx4 acc0 = {0.f, 0.f, 0.f, 0.f}, acc1 = {0.f, 0.f, 0.f, 0.f};

        // ---- x_t @ W1x: independent of h, hides the first h-load RTT ----
        {
            const float* xrow = xs + ((size_t)(t - 1) * BB + myrow) * DIN + q * 8;
            #pragma unroll
            for (int ks = 0; ks < 8; ++ks) {
                floatx4 x0 = *(const floatx4*)(xrow + ks * 32);
                floatx4 x1 = *(const floatx4*)(xrow + ks * 32 + 4);
                shortx8 b;
                b[0] = f2bf(x0[0]); b[1] = f2bf(x0[1]); b[2] = f2bf(x0[2]); b[3] = f2bf(x0[3]);
                b[4] = f2bf(x1[0]); b[5] = f2bf(x1[1]); b[6] = f2bf(x1[2]); b[7] = f2bf(x1[3]);
                acc0 = __builtin_amdgcn_mfma_f32_16x16x32_bf16(wx[0][ks], b, acc0, 0, 0, 0);
                acc1 = __builtin_amdgcn_mfma_f32_16x16x32_bf16(wx[1][ks], b, acc1, 0, 0, 0);
            }
        }

        // ---- h_{t-1} @ W1h: self-validating coalesced chunk pipeline ----
        if (t > 1) {
            LD16(B, 8);
            WAITVALID(A, 0);  CONS16(A, 0);
            LD16(A, 16);
            WAITVALID(B, 8);  CONS16(B, 8);
            LD16(B, 24);
            WAITVALID(A, 16); CONS16(A, 16);
            WAITVALID(B, 24); CONS16(B, 24);
        }

        // ---- tanh, encode epoch bits, two 8B coalesced AGSTs ----
        {
            const int cc = 1 + ((t - 1) % 15);     // code(t), never 0 (=poison)
            short* hp = Hg + (size_t)(t & 1) * HS + wroff;
            u64 p0 = 0, p1 = 0;
            #pragma unroll
            for (int r = 0; r < 4; ++r) {
                const unsigned bit = ((unsigned)cc >> r) & 1u;
                p0 |= ((u64)bf15e(fast_tanh(acc0[r] + bias[0][r]), bit)) << (16 * r);
                p1 |= ((u64)bf15e(fast_tanh(acc1[r] + bias[1][r]), bit)) << (16 * r);
            }
            AGST((u64*)(hp), p0);            // ct=0
            AGST((u64*)(hp + 256), p1);      // ct=1 (+2*128 shorts)
            // fire-and-forget: words self-validate at consumers
        }
    }
}

// out[b][o] = sum_k h[b][k]*W2[k][o] + b2. Final h (t=128 -> parity 0) is in
// fragment layout; decode while staging via AGLD into LDS in natural order.
__global__ __launch_bounds__(256) void readout_kernel(
    const short* __restrict__ Hfin, const float* __restrict__ W2,
    const float* __restrict__ b2, float* __restrict__ out)
{
    const int o  = threadIdx.x;
    const int b0 = blockIdx.x * 4;
    __shared__ u64 hs8[4 * DH / 4];            // [row][col/4], 8 KB
    for (int ch = o; ch < 4 * DH / 4; ch += 256) {
        const int row  = ch >> 8;              // 0..3
        const int col0 = (ch & 255) * 4;       // 0,4,..,1020
        const int rr   = b0 + row;
        const int gmr  = rr >> 5, rt = (rr >> 4) & 1, lrr = rr & 15;
        const int ks   = col0 >> 5, qq = (col0 >> 3) & 3, j0 = col0 & 7;
        const u64* src = (const u64*)(Hfin + (size_t)gmr * GSTRIDE + rt * 16384 +
                                      ks * 512 + qq * 128 + lrr * 8 + j0);
        hs8[ch] = AGLD(src);
    }
    __syncthreads();
    const unsigned* h0 = (const unsigned*)&hs8[0 * 256];
    const unsigned* h1 = (const unsigned*)&hs8[1 * 256];
    const unsigned* h2 = (const unsigned*)&hs8[2 * 256];
    const unsigned* h3 = (const unsigned*)&hs8[3 * 256];
    float a0 = 0.f, a1 = 0.f, a2 = 0.f, a3 = 0.f;
    for (int k2 = 0; k2 < DH / 2; ++k2) {
        float w0 = W2[(2 * k2)     * DOUT + o];
        float w1 = W2[(2 * k2 + 1) * DOUT + o];
        unsigned p0 = h0[k2], p1 = h1[k2], p2 = h2[k2], p3 = h3[k2];
        a0 += __builtin_bit_cast(float, p0 << 16) * w0 + __builtin_bit_cast(float, p0 & 0xffff0000u) * w1;
        a1 += __builtin_bit_cast(float, p1 << 16) * w0 + __builtin_bit_cast(float, p1 & 0xffff0000u) * w1;
        a2 += __builtin_bit_cast(float, p2 << 16) * w0 + __builtin_bit_cast(float, p2 & 0xffff0000u) * w1;
        a3 += __builtin_bit_cast(float, p3 << 16) * w0 + __builtin_bit_cast(float, p3 & 0xffff0000u) * w1;
    }
    const float bias = b2[0];
    out[(b0 + 0) * DOUT + o] = a0 + bias;
    out[(b0 + 1) * DOUT + o] = a1 + bias;
    out[(b0 + 2) * DOUT + o] = a2 + bias;
    out[(b0 + 3) * DOUT + o] = a3 + bias;
}

extern "C" void kernel_launch(void* const* d_in, const int* in_sizes, int n_in,
                              void* d_out, int out_size, void* d_ws, size_t ws_size,
                              hipStream_t stream) {
    (void)in_sizes; (void)n_in; (void)out_size; (void)ws_size;
    const float* xs  = (const float*)d_in[0];   // [128,256,256]
    const float* W1x = (const float*)d_in[1];   // [256,1024]
    const float* W1h = (const float*)d_in[2];   // [1024,1024]
    const float* b1  = (const float*)d_in[3];   // [1024]
    const float* W2  = (const float*)d_in[4];   // [1024,256]
    const float* b2  = (const float*)d_in[5];   // scalar
    float* out = (float*)d_out;                 // [256,256]

    // ws: H parity double buffer (1 MB), fragment layout. No flags, no memset:
    // 0xAA poison -> code 0, never matches any expected code (1..15) -> retry.
    short* Hbuf = (short*)d_ws;

    rnn_steps_kernel<<<dim3(NGM, NGN), 128, 0, stream>>>(xs, W1x, W1h, b1, Hbuf);
    // t=128 -> parity 0 holds h_128
    readout_kernel<<<dim3(BB / 4), 256, 0, stream>>>(Hbuf, W2, b2, out);
}